// Round 1
// baseline (4372.096 us; speedup 1.0000x reference)
//
#include <hip/hip_runtime.h>
#include <hip/hip_fp16.h>

// LSTM: B=64, T=2048, D=128, U=256.
// Phase 1: xz = inputs @ Wx  (f32 tiled GEMM, parallel over all B*T rows)
// Phase 2: one workgroup per batch element (64 WGs, no inter-WG sync).
//          Wh resident on-chip as f16 pairs: 96 pairs/col in VGPRs + 32 in LDS.
//          Dot products via v_dot2_f32_f16 (f32 accumulate). h stored f16 in
//          LDS (error ~1e-3 << 1.85e-2 threshold); c stays f32 in registers.

#define NB 64
#define NT 2048
#define ND 128
#define NU 256
#define N4U 1024

#define WREG 96   // f16 k-pairs per column held in VGPRs
#define WLDS 32   // f16 k-pairs per column held in LDS

typedef _Float16 f16;
typedef _Float16 f16x2 __attribute__((ext_vector_type(2)));
typedef _Float16 f16x8 __attribute__((ext_vector_type(8)));
typedef float f32x4 __attribute__((ext_vector_type(4)));

__device__ __forceinline__ float dot2(f16x2 a, f16x2 b, float c) {
  return __builtin_amdgcn_fdot2(a, b, c, false);
}

__device__ __forceinline__ float sigm(float x) { return 1.0f / (1.0f + __expf(-x)); }
__device__ __forceinline__ float tanh_(float x) { return 1.0f - 2.0f / (__expf(2.0f * x) + 1.0f); }

// ---------------- Phase 1: xz[b][t - t0][j] = sum_k X[b][t][k] * Wx[k][j] ----
// grid: (tc/64, B, 16), block 256. Tile: 64 rows (t) x 64 cols, K=128 staged in LDS.
__global__ __launch_bounds__(256) void xz_gemm(const float* __restrict__ X,
                                               const float* __restrict__ Wx,
                                               float* __restrict__ XZ,
                                               int t0, int tc) {
  __shared__ __align__(16) float xs[64][ND];   // [row][k] 32KB
  __shared__ __align__(16) float ws[ND][64];   // [k][col] 32KB  (total 64KB)
  const int tid = threadIdx.x;
  const int b = blockIdx.y;
  const int row0 = t0 + blockIdx.x * 64;
  const int col0 = blockIdx.z * 64;

  {
    const float* src = X + ((size_t)b * NT + row0) * ND;
#pragma unroll
    for (int ii = 0; ii < 8; ++ii) {
      int q = tid + 256 * ii;          // 0..2047 float4s
      int r = q >> 5;                  // 32 float4 per row
      int k4 = q & 31;
      f32x4 v = *(const f32x4*)(src + (size_t)r * ND + 4 * k4);
      *(f32x4*)&xs[r][4 * k4] = v;
    }
#pragma unroll
    for (int ii = 0; ii < 8; ++ii) {
      int q = tid + 256 * ii;
      int k = q >> 4;                  // 16 float4 per k-row
      int c4 = q & 15;
      f32x4 v = *(const f32x4*)(Wx + (size_t)k * N4U + col0 + 4 * c4);
      *(f32x4*)&ws[k][4 * c4] = v;
    }
  }
  __syncthreads();

  const int tx = tid & 15, ty = tid >> 4;
  float acc[4][4];
#pragma unroll
  for (int i = 0; i < 4; ++i)
#pragma unroll
    for (int j = 0; j < 4; ++j) acc[i][j] = 0.0f;

#pragma unroll 8
  for (int k = 0; k < ND; ++k) {
    f32x4 bv = *(const f32x4*)&ws[k][4 * tx];
    float a0 = xs[4 * ty + 0][k];
    float a1 = xs[4 * ty + 1][k];
    float a2 = xs[4 * ty + 2][k];
    float a3 = xs[4 * ty + 3][k];
#pragma unroll
    for (int j = 0; j < 4; ++j) {
      acc[0][j] += a0 * bv[j];
      acc[1][j] += a1 * bv[j];
      acc[2][j] += a2 * bv[j];
      acc[3][j] += a3 * bv[j];
    }
  }

  float* dst = XZ + ((size_t)b * tc + (row0 - t0)) * N4U + col0;
#pragma unroll
  for (int i = 0; i < 4; ++i) {
    f32x4 v;
#pragma unroll
    for (int j = 0; j < 4; ++j) v[j] = acc[i][j];
    *(f32x4*)(dst + (size_t)(4 * ty + i) * N4U + 4 * tx) = v;
  }
}

// ---------------- Phase 2: sequential scan, one WG per batch ----------------
// block 512: thread t owns output columns j0=t, j1=t+512.
__global__ __launch_bounds__(512, 2) void lstm_seq(const float* __restrict__ Wh,
                                                   const float* __restrict__ bias,
                                                   const float* __restrict__ XZ,
                                                   float* __restrict__ out,
                                                   float* __restrict__ state,
                                                   int t0, int tc) {
  extern __shared__ f16x2 wl[];                 // [2][WLDS][512] = 128KB
  __shared__ float zbuf[N4U];                   // 4KB
  __shared__ __align__(16) f16x2 hbuf[NU / 2];  // 512B (h as f16 pairs)

  const int t = threadIdx.x;
  const int b = blockIdx.x;
  const int j0 = t, j1 = t + 512;

  const float bj0 = bias[j0];
  const float bj1 = bias[j1];

  // Load Wh columns j0, j1 as f16 pairs: first WREG pairs -> VGPRs, rest -> LDS.
  f16x2 wr0[WREG], wr1[WREG];
#pragma unroll
  for (int p = 0; p < WREG; ++p) {
    f16x2 w;
    w.x = (f16)Wh[(size_t)(2 * p) * N4U + j0];
    w.y = (f16)Wh[(size_t)(2 * p + 1) * N4U + j0];
    wr0[p] = w;
    w.x = (f16)Wh[(size_t)(2 * p) * N4U + j1];
    w.y = (f16)Wh[(size_t)(2 * p + 1) * N4U + j1];
    wr1[p] = w;
  }
  for (int p = 0; p < WLDS; ++p) {
    int k = 2 * (WREG + p);
    f16x2 w;
    w.x = (f16)Wh[(size_t)k * N4U + j0];
    w.y = (f16)Wh[(size_t)(k + 1) * N4U + j0];
    wl[(0 * WLDS + p) * 512 + t] = w;
    w.x = (f16)Wh[(size_t)k * N4U + j1];
    w.y = (f16)Wh[(size_t)(k + 1) * N4U + j1];
    wl[(1 * WLDS + p) * 512 + t] = w;
  }

  // init h, c
  float creg = 0.0f, hreg = 0.0f;
  if (t < NU) {
    if (t0 != 0) {
      hreg = state[(size_t)b * 2 * NU + t];
      creg = state[(size_t)b * 2 * NU + NU + t];
    }
    ((f16*)hbuf)[t] = (f16)hreg;
  }
  __syncthreads();

  float xf0 = XZ[((size_t)b * tc) * N4U + j0];
  float xf1 = XZ[((size_t)b * tc) * N4U + j1];

  for (int s = 0; s < tc; ++s) {
    float a0 = xf0 + bj0;
    float a1 = xf1 + bj1;
    if (s + 1 < tc) {  // prefetch next step's xz (hides HBM latency under dots)
      xf0 = XZ[((size_t)b * tc + s + 1) * N4U + j0];
      xf1 = XZ[((size_t)b * tc + s + 1) * N4U + j1];
    }

    const f16x8* hb8 = (const f16x8*)hbuf;  // broadcast b128 reads of h
#pragma unroll
    for (int g = 0; g < WREG / 4; ++g) {
      union { f16x8 v; f16x2 p[4]; } u;
      u.v = hb8[g];
#pragma unroll
      for (int q = 0; q < 4; ++q) {
        a0 = dot2(u.p[q], wr0[4 * g + q], a0);
        a1 = dot2(u.p[q], wr1[4 * g + q], a1);
      }
    }
#pragma unroll
    for (int g = 0; g < WLDS / 4; ++g) {
      union { f16x8 v; f16x2 p[4]; } u;
      u.v = hb8[WREG / 4 + g];
#pragma unroll
      for (int q = 0; q < 4; ++q) {
        int p = 4 * g + q;
        a0 = dot2(u.p[q], wl[(0 * WLDS + p) * 512 + t], a0);
        a1 = dot2(u.p[q], wl[(1 * WLDS + p) * 512 + t], a1);
      }
    }

    zbuf[j0] = a0;
    zbuf[j1] = a1;
    __syncthreads();

    if (t < NU) {
      float zi = zbuf[t];
      float zf = zbuf[t + 256];
      float zg = zbuf[t + 512];
      float zo = zbuf[t + 768];
      float ig = sigm(zi), fg = sigm(zf), og = sigm(zo), gg = tanh_(zg);
      creg = fg * creg + ig * gg;
      hreg = og * tanh_(creg);
      out[((size_t)b * NT + t0 + s) * NU + t] = hreg;
      ((f16*)hbuf)[t] = (f16)hreg;
    }
    __syncthreads();
  }

  if (t < NU) {
    state[(size_t)b * 2 * NU + t] = hreg;
    state[(size_t)b * 2 * NU + NU + t] = creg;
  }
}

extern "C" void kernel_launch(void* const* d_in, const int* in_sizes, int n_in,
                              void* d_out, int out_size, void* d_ws, size_t ws_size,
                              hipStream_t stream) {
  const float* inputs = (const float*)d_in[0];  // [64,2048,128]
  const float* Wx     = (const float*)d_in[1];  // [128,1024]
  const float* Wh     = (const float*)d_in[2];  // [256,1024]
  const float* bias   = (const float*)d_in[3];  // [1024]
  float* out = (float*)d_out;                   // [64,2048,256]

  const size_t state_bytes = (size_t)NB * 2 * NU * sizeof(float);  // 128KB
  float* state = (float*)d_ws;
  float* xzbuf = (float*)((char*)d_ws + state_bytes);

  // choose chunk length (timesteps) fitting in workspace
  size_t avail = (ws_size > state_bytes) ? (ws_size - state_bytes) : 0;
  size_t step_bytes = (size_t)NB * N4U * sizeof(float);  // 256KB per timestep
  long tc_l = (long)(avail / step_bytes);
  int tc = (tc_l > NT) ? NT : (int)tc_l;
  tc = (tc / 64) * 64;
  if (tc < 64) tc = 64;  // assume ws_size >= ~17MB

  const int smem = 2 * WLDS * 512 * (int)sizeof(f16x2);  // 128KB dynamic LDS
  (void)hipFuncSetAttribute((const void*)lstm_seq,
                            hipFuncAttributeMaxDynamicSharedMemorySize, smem);

  for (int t0 = 0; t0 < NT; t0 += tc) {
    int cur = NT - t0;
    if (cur > tc) cur = tc;
    dim3 g1(cur >> 6, NB, 16);
    xz_gemm<<<g1, 256, 0, stream>>>(inputs, Wx, xzbuf, t0, cur);
    lstm_seq<<<NB, 512, smem, stream>>>(Wh, bias, xzbuf, out, state, t0, cur);
  }
}

// Round 3
// 3792.978 us; speedup vs baseline: 1.1527x; 1.1527x over previous
//
#include <hip/hip_runtime.h>
#include <hip/hip_fp16.h>

// LSTM: B=64, T=2048, D=128, U=256.
// Phase 1: xz = inputs @ Wx  (f32 tiled GEMM) -- R1-proven code, unchanged.
// Phase 2: one WG per batch (64 WGs). Wh resident on-chip as f16 pairs:
//          96 pairs/col in VGPRs + 32 pairs/col in LDS (f16x8, b128 reads).
//          R1-proven structure; only deltas vs R1: launch_bounds(512,1) to
//          avoid the wr spill (R1: VGPR=128 < 192 needed), and f16x8 wl.

#define NB 64
#define NT 2048
#define ND 128
#define NU 256
#define N4U 1024

#define WREG 96   // f16 k-pairs per column held in VGPRs
#define WLDS 32   // f16 k-pairs per column held in LDS (as 8 f16x8 groups)

typedef _Float16 f16;
typedef _Float16 f16x2 __attribute__((ext_vector_type(2)));
typedef _Float16 f16x8 __attribute__((ext_vector_type(8)));
typedef float f32x4 __attribute__((ext_vector_type(4)));

__device__ __forceinline__ float dot2(f16x2 a, f16x2 b, float c) {
  return __builtin_amdgcn_fdot2(a, b, c, false);
}

__device__ __forceinline__ float sigm(float x) { return 1.0f / (1.0f + __expf(-x)); }
__device__ __forceinline__ float tanh_(float x) { return 1.0f - 2.0f / (__expf(2.0f * x) + 1.0f); }

// ---------------- Phase 1: xz[b][t - t0][j] = sum_k X[b][t][k] * Wx[k][j] ----
// grid: (tc/64, B, 16), block 256. Tile: 64 rows (t) x 64 cols, K=128 in LDS.
__global__ __launch_bounds__(256) void xz_gemm(const float* __restrict__ X,
                                               const float* __restrict__ Wx,
                                               float* __restrict__ XZ,
                                               int t0, int tc) {
  __shared__ __align__(16) float xs[64][ND];   // [row][k] 32KB
  __shared__ __align__(16) float ws[ND][64];   // [k][col] 32KB
  const int tid = threadIdx.x;
  const int b = blockIdx.y;
  const int row0 = t0 + blockIdx.x * 64;
  const int col0 = blockIdx.z * 64;

  {
    const float* src = X + ((size_t)b * NT + row0) * ND;
#pragma unroll
    for (int ii = 0; ii < 8; ++ii) {
      int q = tid + 256 * ii;          // 0..2047 float4s
      int r = q >> 5;                  // 32 float4 per row
      int k4 = q & 31;
      f32x4 v = *(const f32x4*)(src + (size_t)r * ND + 4 * k4);
      *(f32x4*)&xs[r][4 * k4] = v;
    }
#pragma unroll
    for (int ii = 0; ii < 8; ++ii) {
      int q = tid + 256 * ii;
      int k = q >> 4;                  // 16 float4 per k-row
      int c4 = q & 15;
      f32x4 v = *(const f32x4*)(Wx + (size_t)k * N4U + col0 + 4 * c4);
      *(f32x4*)&ws[k][4 * c4] = v;
    }
  }
  __syncthreads();

  const int tx = tid & 15, ty = tid >> 4;
  float acc[4][4];
#pragma unroll
  for (int i = 0; i < 4; ++i)
#pragma unroll
    for (int j = 0; j < 4; ++j) acc[i][j] = 0.0f;

#pragma unroll 8
  for (int k = 0; k < ND; ++k) {
    f32x4 bv = *(const f32x4*)&ws[k][4 * tx];
    float a0 = xs[4 * ty + 0][k];
    float a1 = xs[4 * ty + 1][k];
    float a2 = xs[4 * ty + 2][k];
    float a3 = xs[4 * ty + 3][k];
#pragma unroll
    for (int j = 0; j < 4; ++j) {
      acc[0][j] += a0 * bv[j];
      acc[1][j] += a1 * bv[j];
      acc[2][j] += a2 * bv[j];
      acc[3][j] += a3 * bv[j];
    }
  }

  float* dst = XZ + ((size_t)b * tc + (row0 - t0)) * N4U + col0;
#pragma unroll
  for (int i = 0; i < 4; ++i) {
    f32x4 v;
#pragma unroll
    for (int j = 0; j < 4; ++j) v[j] = acc[i][j];
    *(f32x4*)(dst + (size_t)(4 * ty + i) * N4U + 4 * tx) = v;
  }
}

// ---------------- Phase 2: sequential scan, one WG per batch ----------------
// block 512: thread t owns output columns j0=t, j1=t+512.
__global__ __launch_bounds__(512, 1) void lstm_seq(const float* __restrict__ Wh,
                                                   const float* __restrict__ bias,
                                                   const float* __restrict__ XZ,
                                                   float* __restrict__ out,
                                                   float* __restrict__ state,
                                                   int t0, int tc) {
  extern __shared__ f16x8 wl[];                 // [2][8][512] f16x8 = 128KB
  __shared__ float zbuf[N4U];                   // 4KB
  __shared__ __align__(16) f16 hbuf[NU];        // 512B

  const int t = threadIdx.x;
  const int b = blockIdx.x;
  const int j0 = t, j1 = t + 512;

  const float bj0 = bias[j0];
  const float bj1 = bias[j1];

  // Wh columns j0, j1 as f16 pairs: first WREG pairs -> VGPRs, rest -> LDS.
  f16x2 wr0[WREG], wr1[WREG];
#pragma unroll
  for (int p = 0; p < WREG; ++p) {
    f16x2 w;
    w.x = (f16)Wh[(size_t)(2 * p) * N4U + j0];
    w.y = (f16)Wh[(size_t)(2 * p + 1) * N4U + j0];
    wr0[p] = w;
    w.x = (f16)Wh[(size_t)(2 * p) * N4U + j1];
    w.y = (f16)Wh[(size_t)(2 * p + 1) * N4U + j1];
    wr1[p] = w;
  }
  for (int g = 0; g < WLDS / 4; ++g) {
    f16x8 w0, w1;
#pragma unroll
    for (int q = 0; q < 4; ++q) {
      int k = 2 * (WREG + 4 * g + q);
      w0[2 * q]     = (f16)Wh[(size_t)k * N4U + j0];
      w0[2 * q + 1] = (f16)Wh[(size_t)(k + 1) * N4U + j0];
      w1[2 * q]     = (f16)Wh[(size_t)k * N4U + j1];
      w1[2 * q + 1] = (f16)Wh[(size_t)(k + 1) * N4U + j1];
    }
    wl[(0 * 8 + g) * 512 + t] = w0;
    wl[(1 * 8 + g) * 512 + t] = w1;
  }

  float creg = 0.0f, hreg = 0.0f;
  if (t < NU) {
    if (t0 != 0) {
      hreg = state[(size_t)b * 2 * NU + t];
      creg = state[(size_t)b * 2 * NU + NU + t];
    }
    hbuf[t] = (f16)hreg;
  }
  __syncthreads();

  float xf0 = XZ[((size_t)b * tc) * N4U + j0];
  float xf1 = XZ[((size_t)b * tc) * N4U + j1];

  for (int s = 0; s < tc; ++s) {
    float a0 = xf0 + bj0;
    float a1 = xf1 + bj1;
    if (s + 1 < tc) {  // prefetch next step's xz
      xf0 = XZ[((size_t)b * tc + s + 1) * N4U + j0];
      xf1 = XZ[((size_t)b * tc + s + 1) * N4U + j1];
    }

    const f16x8* hb8 = (const f16x8*)hbuf;   // broadcast b128 reads of h
#pragma unroll
    for (int g = 0; g < WREG / 4; ++g) {
      union { f16x8 v; f16x2 p[4]; } u;
      u.v = hb8[g];
#pragma unroll
      for (int q = 0; q < 4; ++q) {
        a0 = dot2(u.p[q], wr0[4 * g + q], a0);
        a1 = dot2(u.p[q], wr1[4 * g + q], a1);
      }
    }
#pragma unroll
    for (int g = 0; g < WLDS / 4; ++g) {
      union { f16x8 v; f16x2 p[4]; } u;
      u.v = hb8[WREG / 4 + g];
      union { f16x8 v; f16x2 p[4]; } w0;
      union { f16x8 v; f16x2 p[4]; } w1;
      w0.v = wl[(0 * 8 + g) * 512 + t];
      w1.v = wl[(1 * 8 + g) * 512 + t];
#pragma unroll
      for (int q = 0; q < 4; ++q) {
        a0 = dot2(u.p[q], w0.p[q], a0);
        a1 = dot2(u.p[q], w1.p[q], a1);
      }
    }

    zbuf[j0] = a0;
    zbuf[j1] = a1;
    __syncthreads();

    if (t < NU) {
      float zi = zbuf[t];
      float zf = zbuf[t + 256];
      float zg = zbuf[t + 512];
      float zo = zbuf[t + 768];
      float ig = sigm(zi), fg = sigm(zf), og = sigm(zo), gg = tanh_(zg);
      creg = fg * creg + ig * gg;
      hreg = og * tanh_(creg);
      out[((size_t)b * NT + t0 + s) * NU + t] = hreg;
      hbuf[t] = (f16)hreg;
    }
    __syncthreads();
  }

  if (t < NU) {
    state[(size_t)b * 2 * NU + t] = hreg;
    state[(size_t)b * 2 * NU + NU + t] = creg;
  }
}

extern "C" void kernel_launch(void* const* d_in, const int* in_sizes, int n_in,
                              void* d_out, int out_size, void* d_ws, size_t ws_size,
                              hipStream_t stream) {
  const float* inputs = (const float*)d_in[0];  // [64,2048,128]
  const float* Wx     = (const float*)d_in[1];  // [128,1024]
  const float* Wh     = (const float*)d_in[2];  // [256,1024]
  const float* bias   = (const float*)d_in[3];  // [1024]
  float* out = (float*)d_out;                   // [64,2048,256]

  const size_t state_bytes = (size_t)NB * 2 * NU * sizeof(float);  // 128KB
  float* state = (float*)d_ws;
  float* xzbuf = (float*)((char*)d_ws + state_bytes);

  size_t avail = (ws_size > state_bytes) ? (ws_size - state_bytes) : 0;
  size_t step_bytes = (size_t)NB * N4U * sizeof(float);  // 256KB per timestep
  long tc_l = (long)(avail / step_bytes);
  int tc = (tc_l > NT) ? NT : (int)tc_l;
  tc = (tc / 64) * 64;
  if (tc < 64) tc = 64;

  const int smem = 2 * 8 * 512 * (int)sizeof(f16x8);  // 128KB dynamic LDS
  (void)hipFuncSetAttribute((const void*)lstm_seq,
                            hipFuncAttributeMaxDynamicSharedMemorySize, smem);

  for (int t0 = 0; t0 < NT; t0 += tc) {
    int cur = NT - t0;
    if (cur > tc) cur = tc;
    dim3 g1(cur >> 6, NB, 16);
    xz_gemm<<<g1, 256, 0, stream>>>(inputs, Wx, xzbuf, t0, cur);
    lstm_seq<<<NB, 512, smem, stream>>>(Wh, bias, xzbuf, out, state, t0, cur);
  }
}